// Round 1
// baseline (64.826 us; speedup 1.0000x reference)
//
#include <hip/hip_runtime.h>
#include <hip/hip_bf16.h>

// 3x3 median pool, stride 1, zero-pad 1, fp32 in/out.
// Input: (8, 64, 256, 256) => 512 planes of 256x256.
// Each thread computes 4 contiguous outputs along W (float4 store).

#define S2(a, b) { float _t = fminf(a, b); b = fmaxf(a, b); a = _t; }
#define MN3(a,b,c)        S2(a,b); S2(a,c);
#define MX3(a,b,c)        S2(b,c); S2(a,c);
#define MNMX3(a,b,c)      MX3(a,b,c); S2(a,b);
#define MNMX4(a,b,c,d)    S2(a,b); S2(c,d); S2(a,c); S2(b,d);
#define MNMX5(a,b,c,d,e)  S2(a,b); S2(c,d); MN3(a,c,e); MX3(b,d,e);
#define MNMX6(a,b,c,d,e,f) S2(a,d); S2(b,e); S2(c,f); MN3(a,b,c); MX3(d,e,f);

__global__ __launch_bounds__(256)
void median3x3_kernel(const float* __restrict__ x, float* __restrict__ y, int total4) {
    int idx = blockIdx.x * blockDim.x + threadIdx.x;
    if (idx >= total4) return;

    // W=256 -> 64 float4 groups per row; H=256 rows; plane index above that.
    const int w4 = idx & 63;
    const int h  = (idx >> 6) & 255;
    const int p  = idx >> 14;

    const float* plane = x + ((size_t)p << 16);   // 256*256 floats per plane
    const int c0 = w4 << 2;                        // first output column of this group

    // Load 3 rows x 6 columns (c0-1 .. c0+4) with zero padding.
    float r[3][6];
#pragma unroll
    for (int dr = 0; dr < 3; ++dr) {
        const int hh = h + dr - 1;
        if (hh < 0 || hh > 255) {
#pragma unroll
            for (int j = 0; j < 6; ++j) r[dr][j] = 0.0f;
        } else {
            const float* row = plane + (hh << 8);
            const float4 v = *reinterpret_cast<const float4*>(row + c0);
            r[dr][1] = v.x; r[dr][2] = v.y; r[dr][3] = v.z; r[dr][4] = v.w;
            r[dr][0] = (c0 > 0)       ? row[c0 - 1] : 0.0f;
            r[dr][5] = (c0 + 4 < 256) ? row[c0 + 4] : 0.0f;
        }
    }

    float res[4];
#pragma unroll
    for (int k = 0; k < 4; ++k) {
        float v0 = r[0][k], v1 = r[0][k+1], v2 = r[0][k+2];
        float v3 = r[1][k], v4 = r[1][k+1], v5 = r[1][k+2];
        float v6 = r[2][k], v7 = r[2][k+1], v8 = r[2][k+2];
        // Exact median-of-9 partial sorting network (20 exchanges).
        MNMX6(v0, v1, v2, v3, v4, v5);   // drop min(v0) and max(v5) of first 6
        MNMX5(v1, v2, v3, v4, v6);
        MNMX4(v2, v3, v4, v7);
        MNMX3(v3, v4, v8);
        res[k] = v4;                      // sorted[4] == lower median
    }

    float4 out = make_float4(res[0], res[1], res[2], res[3]);
    *reinterpret_cast<float4*>(y + ((size_t)p << 16) + (h << 8) + c0) = out;
}

extern "C" void kernel_launch(void* const* d_in, const int* in_sizes, int n_in,
                              void* d_out, int out_size, void* d_ws, size_t ws_size,
                              hipStream_t stream) {
    const float* x = (const float*)d_in[0];
    float* y = (float*)d_out;
    const int total4 = out_size / 4;            // 8,388,608 float4 groups
    const int threads = 256;
    const int blocks = (total4 + threads - 1) / threads;
    median3x3_kernel<<<blocks, threads, 0, stream>>>(x, y, total4);
}